// Round 5
// baseline (541.659 us; speedup 1.0000x reference)
//
#include <hip/hip_runtime.h>
#include <math.h>

// Problem constants
#define Bc   8
#define Qn   256
#define Cn   192
#define Hn   20
#define Dn   64
#define En   1500
#define In   5120
#define HIDn 1280
#define BQ   2048            // B*Q rows
#define KSELF 448            // Q + C
#define S1   (BQ*HIDn)       // 2,621,440
#define WSZ  (HIDn*HIDn)     // 1,638,400

typedef __attribute__((ext_vector_type(8))) short bf16x8;
typedef __attribute__((ext_vector_type(4))) float f32x4;

__device__ __forceinline__ short f2bf(float f) {
  union { float f; unsigned u; } x; x.f = f;
  unsigned r = x.u + 0x7fffu + ((x.u >> 16) & 1u);   // RNE
  return (short)(r >> 16);
}
__device__ __forceinline__ float bf2f(short s) {
  union { unsigned u; float f; } x; x.u = ((unsigned)(unsigned short)s) << 16;
  return x.f;
}
__device__ __forceinline__ void gload16(const short* g, short* l) {
  __builtin_amdgcn_global_load_lds(
      (const __attribute__((address_space(1))) void*)g,
      (__attribute__((address_space(3))) void*)l, 16, 0, 0);
}

// ---------------------------------------------------------------------------
// Convert all 8 weight matrices fp32 -> bf16 (blockIdx.y selects matrix)
// ---------------------------------------------------------------------------
__global__ __launch_bounds__(256) void convert_all(
    const float* q, const float* k, const float* v, const float* o,
    const float* cq, const float* co, const float* up, const float* dn,
    short* wq, short* wk, short* wv, short* wo,
    short* wcq, short* wco, short* wup, short* wdn)
{
  const float* src; short* dst; int n;
  switch (blockIdx.y) {
    case 0: src = q;  dst = wq;  n = WSZ; break;
    case 1: src = k;  dst = wk;  n = WSZ; break;
    case 2: src = v;  dst = wv;  n = WSZ; break;
    case 3: src = o;  dst = wo;  n = WSZ; break;
    case 4: src = cq; dst = wcq; n = WSZ; break;
    case 5: src = co; dst = wco; n = WSZ; break;
    case 6: src = up; dst = wup; n = HIDn * In; break;
    default: src = dn; dst = wdn; n = HIDn * In; break;
  }
  const int i = (blockIdx.x * 256 + threadIdx.x) * 8;
  if (i >= n) return;
  const float4 a = *reinterpret_cast<const float4*>(src + i);
  const float4 b = *reinterpret_cast<const float4*>(src + i + 4);
  bf16x8 t;
  t[0] = f2bf(a.x); t[1] = f2bf(a.y); t[2] = f2bf(a.z); t[3] = f2bf(a.w);
  t[4] = f2bf(b.x); t[5] = f2bf(b.y); t[6] = f2bf(b.z); t[7] = f2bf(b.w);
  *reinterpret_cast<bf16x8*>(dst + i) = t;
}

// ---------------------------------------------------------------------------
// LayerNorm: fp32 in, bf16 out. One 256-thread block per row of 1280.
// ---------------------------------------------------------------------------
__global__ __launch_bounds__(256) void layernorm_k(
    const float* __restrict__ in, const float* __restrict__ w,
    const float* __restrict__ b, short* __restrict__ out)
{
  const int row = blockIdx.x;
  const float* x = in + (size_t)row * HIDn;
  float v[5], s = 0.f, s2 = 0.f;
#pragma unroll
  for (int i = 0; i < 5; ++i) {
    float t = x[threadIdx.x + 256 * i];
    v[i] = t; s += t; s2 += t * t;
  }
#pragma unroll
  for (int off = 1; off < 64; off <<= 1) {
    s  += __shfl_xor(s,  off, 64);
    s2 += __shfl_xor(s2, off, 64);
  }
  __shared__ float red[8];
  const int wave = threadIdx.x >> 6, lane = threadIdx.x & 63;
  if (lane == 0) { red[wave] = s; red[wave + 4] = s2; }
  __syncthreads();
  s  = red[0] + red[1] + red[2] + red[3];
  s2 = red[4] + red[5] + red[6] + red[7];
  const float mu  = s / HIDn;
  const float var = s2 / HIDn - mu * mu;
  const float rs  = rsqrtf(var + 1e-5f);
#pragma unroll
  for (int i = 0; i < 5; ++i) {
    const int c = threadIdx.x + 256 * i;
    out[(size_t)row * HIDn + c] = f2bf((v[i] - mu) * rs * w[c] + b[c]);
  }
}

// ---------------------------------------------------------------------------
// NT GEMM, bf16 in via global_load_lds, fragment-order LDS, BK=64.
// XCD-chunk swizzled 3-D grid (x=m-tile, y=n-tile, z=K-split piece).
// 4 waves as 2x2; wave computes (BM/2)x(BN/2) via FM x FN 16x16 frags.
// K = per-piece K length; LDK = row stride of A and W; piece offset bz*K.
// MODE 0: fp32 out0 = acc + bias + resid
// MODE 1: bf16 out0 = (acc + bias) * scale
// MODE 2: bf16 out0 = gelu(acc + bias)
// MODE 3: QKV triple bf16 out; region by n0/1280; q region scaled 0.125
// MODE 4: fp32 raw partial (out0 for z=0, out1 for z=1)
// ---------------------------------------------------------------------------
template<int BM, int BN, int MODE>
__global__ __launch_bounds__(256) void gemm_bk64(
    const short* __restrict__ A, const short* __restrict__ W,
    const float* __restrict__ bias, const float* __restrict__ resid,
    void* __restrict__ out0, void* __restrict__ out1, void* __restrict__ out2,
    const float* __restrict__ b1, const float* __restrict__ b2,
    int N, int K, int LDK, float scale)
{
  constexpr int FM = BM / 32, FN = BN / 32;
  __shared__ __align__(16) short Alds[BM * 64];
  __shared__ __align__(16) short Blds[BN * 64];

  // bijective XCD-chunk swizzle over the linearized grid (T % 8 == 0)
  const int GX = gridDim.x, GY = gridDim.y;
  int lid = blockIdx.x + GX * (blockIdx.y + GY * blockIdx.z);
  const int cpx = (GX * GY * gridDim.z) >> 3;
  lid = (lid & 7) * cpx + (lid >> 3);
  const int bx = lid % GX;
  const int by = (lid / GX) % GY;
  const int bz = lid / (GX * GY);

  const int tid = threadIdx.x, lane = tid & 63, wave = tid >> 6;
  const int wr = wave >> 1, wc = wave & 1;
  const int m0 = bx * BM, n0 = by * BN;
  const int lr = lane & 15;               // fragment row
  const int kc = (lane >> 4) * 8;         // fragment k sub-offset
  const size_t koff = (size_t)bz * K;

  f32x4 acc[FM][FN];
#pragma unroll
  for (int mi = 0; mi < FM; ++mi)
#pragma unroll
    for (int ni = 0; ni < FN; ++ni)
      acc[mi][ni] = (f32x4){0.f, 0.f, 0.f, 0.f};

  const int nk = K >> 6;
  for (int kt = 0; kt < nk; ++kt) {
    const int k0 = kt << 6;
#pragma unroll
    for (int j = 0; j < BM / 32; ++j) {
      const int i = wave + 4 * j;          // issue index in [0, BM/8)
      const int rb = i >> 1, kk = i & 1;
      gload16(A + (size_t)(m0 + rb * 16 + lr) * LDK + koff + k0 + kk * 32 + kc,
              &Alds[i * 512]);
    }
#pragma unroll
    for (int j = 0; j < BN / 32; ++j) {
      const int i = wave + 4 * j;
      const int rb = i >> 1, kk = i & 1;
      gload16(W + (size_t)(n0 + rb * 16 + lr) * LDK + koff + k0 + kk * 32 + kc,
              &Blds[i * 512]);
    }
    __syncthreads();
    bf16x8 af[2][FM], bfv[2][FN];
#pragma unroll
    for (int kk = 0; kk < 2; ++kk) {
#pragma unroll
      for (int mi = 0; mi < FM; ++mi)
        af[kk][mi] = *reinterpret_cast<const bf16x8*>(
            &Alds[((wr * FM + mi) * 2 + kk) * 512 + lane * 8]);
#pragma unroll
      for (int ni = 0; ni < FN; ++ni)
        bfv[kk][ni] = *reinterpret_cast<const bf16x8*>(
            &Blds[((wc * FN + ni) * 2 + kk) * 512 + lane * 8]);
    }
#pragma unroll
    for (int kk = 0; kk < 2; ++kk)
#pragma unroll
      for (int mi = 0; mi < FM; ++mi)
#pragma unroll
        for (int ni = 0; ni < FN; ++ni)
          acc[mi][ni] = __builtin_amdgcn_mfma_f32_16x16x32_bf16(
              af[kk][mi], bfv[kk][ni], acc[mi][ni], 0, 0, 0);
    __syncthreads();
  }

  // epilogue: C/D col = lane&15, row = (lane>>4)*4 + reg
  const int cn = lane & 15;
  const int rb = (lane >> 4) * 4;
#pragma unroll
  for (int mi = 0; mi < FM; ++mi)
#pragma unroll
    for (int ni = 0; ni < FN; ++ni)
#pragma unroll
      for (int j = 0; j < 4; ++j) {
        const int row = m0 + wr * (BM / 2) + mi * 16 + rb + j;
        const int col = n0 + wc * (BN / 2) + ni * 16 + cn;
        const float a = acc[mi][ni][j];
        if (MODE == 0) {
          ((float*)out0)[(size_t)row * N + col] =
              a + bias[col] + resid[(size_t)row * N + col];
        } else if (MODE == 1) {
          ((short*)out0)[(size_t)row * N + col] = f2bf((a + bias[col]) * scale);
        } else if (MODE == 2) {
          float t = a + bias[col];
          t = 0.5f * t * (1.f + erff(t * 0.70710678118654752f));
          ((short*)out0)[(size_t)row * N + col] = f2bf(t);
        } else if (MODE == 3) {
          const int rg  = n0 / 1280;
          const int cl  = col - rg * 1280;
          short* op     = rg == 0 ? (short*)out0 : rg == 1 ? (short*)out1 : (short*)out2;
          const float* bp = rg == 0 ? bias : rg == 1 ? b1 : b2;
          const float sc  = rg == 0 ? 0.125f : 1.f;
          op[(size_t)row * 1280 + cl] = f2bf((a + bp[cl]) * sc);
        } else {
          float* op = bz == 0 ? (float*)out0 : (float*)out1;
          op[(size_t)row * N + col] = a;
        }
      }
}

// ---------------------------------------------------------------------------
// down-proj reduction: out = p0 + p1 + bias + resid   (fp32, float4)
// ---------------------------------------------------------------------------
__global__ __launch_bounds__(256) void reduce_down(
    const float* __restrict__ p0, const float* __restrict__ p1,
    const float* __restrict__ resid, const float* __restrict__ bias,
    float* __restrict__ out)
{
  const size_t i = ((size_t)blockIdx.x * 256 + threadIdx.x) * 4;
  if (i >= (size_t)S1) return;
  const int col = (int)(i % HIDn);
  const float4 a = *reinterpret_cast<const float4*>(p0 + i);
  const float4 b = *reinterpret_cast<const float4*>(p1 + i);
  const float4 r = *reinterpret_cast<const float4*>(resid + i);
  const float4 bi = *reinterpret_cast<const float4*>(bias + col);
  float4 o;
  o.x = a.x + b.x + r.x + bi.x;
  o.y = a.y + b.y + r.y + bi.y;
  o.z = a.z + b.z + r.z + bi.z;
  o.w = a.w + b.w + r.w + bi.w;
  *reinterpret_cast<float4*>(out + i) = o;
}

// ---------------------------------------------------------------------------
// MFMA flash attention. Q/Kn/Vn/out bf16; past/cross K/V fp32.
// 1-D grid of 640 blocks, XCD-chunk swizzled so the 4 q-tiles of one (b,h)
// land on the same XCD (L2 reuse of the K/V panel).
// Block = 4 waves; each wave owns 16 q-rows of a 64-row Q tile; 64-key chunks.
// ---------------------------------------------------------------------------
template<bool HASMASK>
__global__ __launch_bounds__(256) void attn_mfma(
    const short* __restrict__ Qb, const float* __restrict__ Kp,
    const float* __restrict__ Vp, const short* __restrict__ Kn,
    const short* __restrict__ Vn, const float* __restrict__ mask,
    short* __restrict__ Ob, int Cp, int KT)
{
  const int orig = blockIdx.x;                  // 640 = 4*Hn*Bc
  const int idx  = (orig & 7) * 80 + (orig >> 3);
  const int qt = idx & 3;
  const int h  = (idx >> 2) % Hn;
  const int b  = idx / (4 * Hn);
  const int tid = threadIdx.x, lane = tid & 63, wave = tid >> 6;
  const int q0 = qt * 64;
  const int cn = lane & 15;
  const int hg = lane >> 4;
  const int rb = hg * 4;

  __shared__ __align__(16) short k_s[64][72];
  __shared__ __align__(16) short vt_s[64][72];
  __shared__ __align__(16) short p_s[4][16][72];

  bf16x8 aq[2];
  {
    const short* qrow = Qb + (size_t)(b * Qn + q0 + wave * 16 + cn) * HIDn + h * 64;
    aq[0] = *reinterpret_cast<const bf16x8*>(qrow + hg * 8);
    aq[1] = *reinterpret_cast<const bf16x8*>(qrow + 32 + hg * 8);
  }

  float mrun[4] = {-1e30f, -1e30f, -1e30f, -1e30f};
  float lrun[4] = {0.f, 0.f, 0.f, 0.f};
  f32x4 oacc[4];
#pragma unroll
  for (int t = 0; t < 4; ++t) oacc[t] = (f32x4){0.f, 0.f, 0.f, 0.f};

  const int nchunk = (KT + 63) >> 6;
  for (int ci = 0; ci < nchunk; ++ci) {
    const int c0 = ci * 64;
    // stage K row-major + V transposed/swizzled, 8-elem chunks
    for (int i = tid; i < 64 * 8; i += 256) {
      const int key = i >> 3, d8 = (i & 7) * 8;
      const int gk = c0 + key;
      bf16x8 kv8 = (bf16x8)0, vv8 = (bf16x8)0;
      if (gk < KT) {
        if (gk < Cp) {
          const size_t off = (((size_t)b * Hn + h) * (size_t)Cp + gk) * 64 + d8;
          const float4 ka = *reinterpret_cast<const float4*>(Kp + off);
          const float4 kb = *reinterpret_cast<const float4*>(Kp + off + 4);
          const float4 va = *reinterpret_cast<const float4*>(Vp + off);
          const float4 vb = *reinterpret_cast<const float4*>(Vp + off + 4);
          kv8[0] = f2bf(ka.x); kv8[1] = f2bf(ka.y); kv8[2] = f2bf(ka.z); kv8[3] = f2bf(ka.w);
          kv8[4] = f2bf(kb.x); kv8[5] = f2bf(kb.y); kv8[6] = f2bf(kb.z); kv8[7] = f2bf(kb.w);
          vv8[0] = f2bf(va.x); vv8[1] = f2bf(va.y); vv8[2] = f2bf(va.z); vv8[3] = f2bf(va.w);
          vv8[4] = f2bf(vb.x); vv8[5] = f2bf(vb.y); vv8[6] = f2bf(vb.z); vv8[7] = f2bf(vb.w);
        } else {
          const size_t off = (size_t)(b * Qn + (gk - Cp)) * HIDn + h * 64 + d8;
          kv8 = *reinterpret_cast<const bf16x8*>(Kn + off);
          vv8 = *reinterpret_cast<const bf16x8*>(Vn + off);
        }
      }
      *reinterpret_cast<bf16x8*>(&k_s[key][d8]) = kv8;
      const int g = key >> 3, o = key & 7, f = (d8 >> 3) & 7;
#pragma unroll
      for (int j = 0; j < 8; ++j)
        vt_s[d8 + j][((g ^ f) << 3) | o] = vv8[j];
    }
    __syncthreads();

    // QK^T
    f32x4 sacc[4];
#pragma unroll
    for (int t = 0; t < 4; ++t) sacc[t] = (f32x4){0.f, 0.f, 0.f, 0.f};
#pragma unroll
    for (int t = 0; t < 4; ++t)
#pragma unroll
      for (int kk = 0; kk < 2; ++kk) {
        const bf16x8 bk = *reinterpret_cast<const bf16x8*>(&k_s[t * 16 + cn][kk * 32 + hg * 8]);
        sacc[t] = __builtin_amdgcn_mfma_f32_16x16x32_bf16(aq[kk], bk, sacc[t], 0, 0, 0);
      }

    float sc[4][4];
#pragma unroll
    for (int t = 0; t < 4; ++t) {
      const int key = c0 + t * 16 + cn;
      const bool valid = key < KT;
#pragma unroll
      for (int j = 0; j < 4; ++j) {
        float v = sacc[t][j];
        if (HASMASK && valid)
          v += mask[((size_t)(b * Qn) + q0 + wave * 16 + rb + j) * KT + key];
        sc[t][j] = valid ? v : -1e30f;
      }
    }

    // online softmax
#pragma unroll
    for (int j = 0; j < 4; ++j) {
      float mx = fmaxf(fmaxf(sc[0][j], sc[1][j]), fmaxf(sc[2][j], sc[3][j]));
#pragma unroll
      for (int off = 1; off < 16; off <<= 1) mx = fmaxf(mx, __shfl_xor(mx, off, 64));
      const float mnew  = fmaxf(mrun[j], mx);
      const float alpha = __expf(mrun[j] - mnew);
      float ps = 0.f;
#pragma unroll
      for (int t = 0; t < 4; ++t) {
        const float p = __expf(sc[t][j] - mnew);
        sc[t][j] = p; ps += p;
      }
#pragma unroll
      for (int off = 1; off < 16; off <<= 1) ps += __shfl_xor(ps, off, 64);
      lrun[j] = lrun[j] * alpha + ps;
      mrun[j] = mnew;
#pragma unroll
      for (int t = 0; t < 4; ++t) oacc[t][j] *= alpha;
    }

    // P -> per-wave LDS slice (same-wave RAW)
#pragma unroll
    for (int t = 0; t < 4; ++t)
#pragma unroll
      for (int j = 0; j < 4; ++j)
        p_s[wave][rb + j][t * 16 + cn] = f2bf(sc[t][j]);

    // PV
    const bf16x8 ap0 = *reinterpret_cast<const bf16x8*>(&p_s[wave][cn][hg * 8]);
    const bf16x8 ap1 = *reinterpret_cast<const bf16x8*>(&p_s[wave][cn][32 + hg * 8]);
#pragma unroll
    for (int t = 0; t < 4; ++t) {
      const int d  = t * 16 + cn;
      const int fd = (d >> 3) & 7;
      const bf16x8 bv0 = *reinterpret_cast<const bf16x8*>(&vt_s[d][((hg)     ^ fd) << 3]);
      const bf16x8 bv1 = *reinterpret_cast<const bf16x8*>(&vt_s[d][((4 + hg) ^ fd) << 3]);
      oacc[t] = __builtin_amdgcn_mfma_f32_16x16x32_bf16(ap0, bv0, oacc[t], 0, 0, 0);
      oacc[t] = __builtin_amdgcn_mfma_f32_16x16x32_bf16(ap1, bv1, oacc[t], 0, 0, 0);
    }
    __syncthreads();
  }

#pragma unroll
  for (int t = 0; t < 4; ++t)
#pragma unroll
    for (int j = 0; j < 4; ++j)
      Ob[(size_t)(b * Qn + q0 + wave * 16 + rb + j) * HIDn + h * 64 + t * 16 + cn] =
          f2bf(oacc[t][j] / lrun[j]);
}

// ---------------------------------------------------------------------------
// present_key/value: bf16 new K/V rows (Q-C)..Q-1 -> fp32 (B,H,C,D)
// ---------------------------------------------------------------------------
__global__ __launch_bounds__(256) void copy_present(
    const short* __restrict__ kn, const short* __restrict__ vn,
    float* __restrict__ outk, float* __restrict__ outv)
{
  const int idx = blockIdx.x * 256 + threadIdx.x;      // over B*H*C*8 chunks
  if (idx >= Bc * Hn * Cn * 8) return;
  const int d8 = (idx & 7) * 8;
  int t = idx >> 3;
  const int c = t % Cn; t /= Cn;
  const int h = t % Hn;
  const int b = t / Hn;
  const size_t src = (size_t)(b * Qn + (Qn - Cn) + c) * HIDn + h * 64 + d8;
  const size_t dst = (((size_t)b * Hn + h) * Cn + c) * 64 + d8;
  const bf16x8 kv = *reinterpret_cast<const bf16x8*>(kn + src);
  const bf16x8 vv = *reinterpret_cast<const bf16x8*>(vn + src);
#pragma unroll
  for (int j = 0; j < 8; ++j) {
    outk[dst + j] = bf2f(kv[j]);
    outv[dst + j] = bf2f(vv[j]);
  }
}

// ---------------------------------------------------------------------------
extern "C" void kernel_launch(void* const* d_in, const int* in_sizes, int n_in,
                              void* d_out, int out_size, void* d_ws, size_t ws_size,
                              hipStream_t stream)
{
  const float* hidden  = (const float*)d_in[0];
  const float* mask    = (const float*)d_in[1];
  const float* past_k  = (const float*)d_in[2];
  const float* past_v  = (const float*)d_in[3];
  const float* cross_k = (const float*)d_in[4];
  const float* cross_v = (const float*)d_in[5];
  const float* q_w  = (const float*)d_in[6];  const float* q_b  = (const float*)d_in[7];
  const float* k_w  = (const float*)d_in[8];  const float* k_b  = (const float*)d_in[9];
  const float* v_w  = (const float*)d_in[10]; const float* v_b  = (const float*)d_in[11];
  const float* o_w  = (const float*)d_in[12]; const float* o_b  = (const float*)d_in[13];
  const float* cq_w = (const float*)d_in[14]; const float* cq_b = (const float*)d_in[15];
  const float* co_w = (const float*)d_in[16]; const float* co_b = (const float*)d_in[17];
  const float* up_w = (const float*)d_in[18]; const float* up_b = (const float*)d_in[19];
  const float* dn_w = (const float*)d_in[20]; const float* dn_b = (const float*)d_in[21];
  const float* ln1w = (const float*)d_in[22]; const float* ln1b = (const float*)d_in[23];
  const float* ln2w = (const float*)d_in[24]; const float* ln2b = (const float*)d_in[25];
  const float* ln3w = (const float*)d_in[26]; const float* ln3b = (const float*)d_in[27];

  // workspace layout (bf16 weights, bf16 activations, fp32 residuals)
  short* wq  = (short*)d_ws;                    // qkv weights contiguous
  short* wk  = wq  + (size_t)WSZ;
  short* wv  = wk  + (size_t)WSZ;
  short* wo  = wv  + (size_t)WSZ;
  short* wcq = wo  + (size_t)WSZ;
  short* wco = wcq + (size_t)WSZ;
  short* wup = wco + (size_t)WSZ;
  short* wdn = wup + (size_t)HIDn * In;
  short* xb  = wdn + (size_t)HIDn * In;         // LN outputs (reused x1,x2,x3)
  short* qb  = xb  + (size_t)S1;                // q, reused as cq
  short* kb  = qb  + (size_t)S1;
  short* vb  = kb  + (size_t)S1;
  short* ab  = vb  + (size_t)S1;                // attn outputs
  short* upa = ab  + (size_t)S1;                // gelu(up) activations
  float* h1  = (float*)(upa + (size_t)BQ * In);
  float* h2  = h1 + (size_t)S1;
  // down-proj split-K partials alias the (dead-by-then) qb..ab region
  float* p0  = (float*)qb;                      // spans qb+kb (10.49 MB)
  float* p1  = (float*)vb;                      // spans vb+ab (10.49 MB)

  float* out_h  = (float*)d_out;
  float* out_pk = out_h + (size_t)S1;
  float* out_pv = out_pk + (size_t)(Bc * Hn * Cn * Dn);

  const dim3 blk(256);
  const dim3 gconv(3200, 8);
  const dim3 gqkv(32, 30);         // 2048/64 x 3840/128  (960 blocks)
  const dim3 g64(32, 20);          // 2048/64 x 1280/64   (640 blocks)
  const dim3 gup(32, 40);          // 2048/64 x 5120/128  (1280 blocks)
  const dim3 gdn(32, 20, 2);       // split-K=2           (1280 blocks)
  const dim3 gattn(640);           // 4 * Hn * Bc, XCD-swizzled in-kernel

  // weights -> bf16
  convert_all<<<gconv, blk, 0, stream>>>(q_w, k_w, v_w, o_w, cq_w, co_w, up_w, dn_w,
                                         wq, wk, wv, wo, wcq, wco, wup, wdn);
  // x1 = LN1(hidden)
  layernorm_k<<<BQ, blk, 0, stream>>>(hidden, ln1w, ln1b, xb);
  // q,k,v fused GEMM (q scaled 0.125 in epilogue)
  gemm_bk64<64, 128, 3><<<gqkv, blk, 0, stream>>>(xb, wq, q_b, nullptr,
      qb, kb, vb, k_b, v_b, 3840, HIDn, HIDn, 1.f);
  // present kv
  copy_present<<<(Bc * Hn * Cn * 8 + 255) / 256, blk, 0, stream>>>(kb, vb, out_pk, out_pv);
  // self attention -> ab
  attn_mfma<true><<<gattn, blk, 0, stream>>>(qb, past_k, past_v, kb, vb, mask, ab, Cn, KSELF);
  // h1 = hidden + ab Wo^T + bo
  gemm_bk64<64, 64, 0><<<g64, blk, 0, stream>>>(ab, wo, o_b, hidden,
      h1, nullptr, nullptr, nullptr, nullptr, HIDn, HIDn, HIDn, 1.f);
  // x2 = LN2(h1)
  layernorm_k<<<BQ, blk, 0, stream>>>(h1, ln2w, ln2b, xb);
  // cq = (x2 Wcq^T + b)*0.125  (reuse qb)
  gemm_bk64<64, 64, 1><<<g64, blk, 0, stream>>>(xb, wcq, cq_b, nullptr,
      qb, nullptr, nullptr, nullptr, nullptr, HIDn, HIDn, HIDn, 0.125f);
  // cross attention -> ab
  attn_mfma<false><<<gattn, blk, 0, stream>>>(qb, cross_k, cross_v,
      (const short*)nullptr, (const short*)nullptr, nullptr, ab, En, En);
  // h2 = h1 + ab Wco^T + b
  gemm_bk64<64, 64, 0><<<g64, blk, 0, stream>>>(ab, wco, co_b, h1,
      h2, nullptr, nullptr, nullptr, nullptr, HIDn, HIDn, HIDn, 1.f);
  // x3 = LN3(h2)
  layernorm_k<<<BQ, blk, 0, stream>>>(h2, ln3w, ln3b, xb);
  // upa = gelu(x3 Wup^T + b)
  gemm_bk64<64, 128, 2><<<gup, blk, 0, stream>>>(xb, wup, up_b, nullptr,
      upa, nullptr, nullptr, nullptr, nullptr, In, HIDn, HIDn, 1.f);
  // down-proj split-K=2 partials (p0: k 0..2559, p1: k 2560..5119)
  gemm_bk64<64, 64, 4><<<gdn, blk, 0, stream>>>(upa, wdn, nullptr, nullptr,
      p0, p1, nullptr, nullptr, nullptr, HIDn, In / 2, In, 1.f);
  // out_h = p0 + p1 + dn_b + h2
  reduce_down<<<(S1 / 4 + 255) / 256, blk, 0, stream>>>(p0, p1, h2, dn_b, out_h);
}

// Round 6
// 539.729 us; speedup vs baseline: 1.0036x; 1.0036x over previous
//
#include <hip/hip_runtime.h>
#include <math.h>

// Problem constants
#define Bc   8
#define Qn   256
#define Cn   192
#define Hn   20
#define Dn   64
#define En   1500
#define In   5120
#define HIDn 1280
#define BQ   2048            // B*Q rows
#define KSELF 448            // Q + C
#define EPAD 1536            // cross keys padded to 24*64
#define S1   (BQ*HIDn)       // 2,621,440
#define WSZ  (HIDn*HIDn)     // 1,638,400
#define BH   (Bc*Hn)         // 160

typedef __attribute__((ext_vector_type(8))) short bf16x8;
typedef __attribute__((ext_vector_type(4))) float f32x4;

__device__ __forceinline__ short f2bf(float f) {
  union { float f; unsigned u; } x; x.f = f;
  unsigned r = x.u + 0x7fffu + ((x.u >> 16) & 1u);   // RNE
  return (short)(r >> 16);
}
__device__ __forceinline__ float bf2f(short s) {
  union { unsigned u; float f; } x; x.u = ((unsigned)(unsigned short)s) << 16;
  return x.f;
}
__device__ __forceinline__ void gload16(const short* g, short* l) {
  __builtin_amdgcn_global_load_lds(
      (const __attribute__((address_space(1))) void*)g,
      (__attribute__((address_space(3))) void*)l, 16, 0, 0);
}
__device__ __forceinline__ bf16x8 cvt8(const float* p) {
  const float4 a = *reinterpret_cast<const float4*>(p);
  const float4 b = *reinterpret_cast<const float4*>(p + 4);
  bf16x8 t;
  t[0] = f2bf(a.x); t[1] = f2bf(a.y); t[2] = f2bf(a.z); t[3] = f2bf(a.w);
  t[4] = f2bf(b.x); t[5] = f2bf(b.y); t[6] = f2bf(b.z); t[7] = f2bf(b.w);
  return t;
}

// ---------------------------------------------------------------------------
// Convert all 8 weight matrices fp32 -> bf16 (blockIdx.y selects matrix)
// ---------------------------------------------------------------------------
__global__ __launch_bounds__(256) void convert_all(
    const float* q, const float* k, const float* v, const float* o,
    const float* cq, const float* co, const float* up, const float* dn,
    short* wq, short* wk, short* wv, short* wo,
    short* wcq, short* wco, short* wup, short* wdn)
{
  const float* src; short* dst; int n;
  switch (blockIdx.y) {
    case 0: src = q;  dst = wq;  n = WSZ; break;
    case 1: src = k;  dst = wk;  n = WSZ; break;
    case 2: src = v;  dst = wv;  n = WSZ; break;
    case 3: src = o;  dst = wo;  n = WSZ; break;
    case 4: src = cq; dst = wcq; n = WSZ; break;
    case 5: src = co; dst = wco; n = WSZ; break;
    case 6: src = up; dst = wup; n = HIDn * In; break;
    default: src = dn; dst = wdn; n = HIDn * In; break;
  }
  const int i = (blockIdx.x * 256 + threadIdx.x) * 8;
  if (i >= n) return;
  *reinterpret_cast<bf16x8*>(dst + i) = cvt8(src + i);
}

// ---------------------------------------------------------------------------
// Cross K/V -> bf16 row-major caches padded to EPAD keys (zeros in pad)
// ---------------------------------------------------------------------------
__global__ __launch_bounds__(256) void prep_cross(
    const float* __restrict__ K, const float* __restrict__ V,
    short* __restrict__ Kc, short* __restrict__ Vc)
{
  const size_t idx = (size_t)blockIdx.x * 256 + threadIdx.x;  // BH*EPAD*8
  const int d8 = (int)(idx & 7) * 8;
  const size_t t = idx >> 3;
  const int key = (int)(t % EPAD);
  const int bh  = (int)(t / EPAD);
  bf16x8 kv = (bf16x8)0, vv = (bf16x8)0;
  if (key < En) {
    const size_t off = ((size_t)bh * En + key) * 64 + d8;
    kv = cvt8(K + off);
    vv = cvt8(V + off);
  }
  const size_t dst = ((size_t)bh * EPAD + key) * 64 + d8;
  *reinterpret_cast<bf16x8*>(Kc + dst) = kv;
  *reinterpret_cast<bf16x8*>(Vc + dst) = vv;
}

// ---------------------------------------------------------------------------
// Self K/V caches: keys 0..191 from past fp32, 192..447 from new bf16
// ---------------------------------------------------------------------------
__global__ __launch_bounds__(256) void prep_self(
    const float* __restrict__ Kp, const float* __restrict__ Vp,
    const short* __restrict__ kn, const short* __restrict__ vn,
    short* __restrict__ Kc, short* __restrict__ Vc)
{
  const size_t idx = (size_t)blockIdx.x * 256 + threadIdx.x;  // BH*KSELF*8
  const int d8 = (int)(idx & 7) * 8;
  const size_t t = idx >> 3;
  const int key = (int)(t % KSELF);
  const int bh  = (int)(t / KSELF);
  bf16x8 kv, vv;
  if (key < Cn) {
    const size_t off = ((size_t)bh * Cn + key) * 64 + d8;
    kv = cvt8(Kp + off);
    vv = cvt8(Vp + off);
  } else {
    const int b = bh / Hn, h = bh % Hn;
    const size_t off = ((size_t)(b * Qn + (key - Cn))) * HIDn + h * 64 + d8;
    kv = *reinterpret_cast<const bf16x8*>(kn + off);
    vv = *reinterpret_cast<const bf16x8*>(vn + off);
  }
  const size_t dst = ((size_t)bh * KSELF + key) * 64 + d8;
  *reinterpret_cast<bf16x8*>(Kc + dst) = kv;
  *reinterpret_cast<bf16x8*>(Vc + dst) = vv;
}

// ---------------------------------------------------------------------------
// LayerNorm: fp32 in, bf16 out. One 256-thread block per row of 1280.
// ---------------------------------------------------------------------------
__global__ __launch_bounds__(256) void layernorm_k(
    const float* __restrict__ in, const float* __restrict__ w,
    const float* __restrict__ b, short* __restrict__ out)
{
  const int row = blockIdx.x;
  const float* x = in + (size_t)row * HIDn;
  float v[5], s = 0.f, s2 = 0.f;
#pragma unroll
  for (int i = 0; i < 5; ++i) {
    float t = x[threadIdx.x + 256 * i];
    v[i] = t; s += t; s2 += t * t;
  }
#pragma unroll
  for (int off = 1; off < 64; off <<= 1) {
    s  += __shfl_xor(s,  off, 64);
    s2 += __shfl_xor(s2, off, 64);
  }
  __shared__ float red[8];
  const int wave = threadIdx.x >> 6, lane = threadIdx.x & 63;
  if (lane == 0) { red[wave] = s; red[wave + 4] = s2; }
  __syncthreads();
  s  = red[0] + red[1] + red[2] + red[3];
  s2 = red[4] + red[5] + red[6] + red[7];
  const float mu  = s / HIDn;
  const float var = s2 / HIDn - mu * mu;
  const float rs  = rsqrtf(var + 1e-5f);
#pragma unroll
  for (int i = 0; i < 5; ++i) {
    const int c = threadIdx.x + 256 * i;
    out[(size_t)row * HIDn + c] = f2bf((v[i] - mu) * rs * w[c] + b[c]);
  }
}

// ---------------------------------------------------------------------------
// NT GEMM, bf16 in via global_load_lds, fragment-order LDS, BK=64.
// 4 waves as 2x2; wave computes (BM/2)x(BN/2) via FM x FN 16x16 frags.
// K = per-piece K length; LDK = row stride; piece offset blockIdx.z*K.
// MODE 0: fp32 out0 = acc + bias + resid
// MODE 1: bf16 out0 = (acc + bias) * scale
// MODE 2: bf16 out0 = gelu(acc + bias)
// MODE 3: QKV triple bf16 out; region by n0/1280; q region scaled 0.125
// MODE 4: fp32 raw partial (out0 for z=0, out1 for z=1)
// ---------------------------------------------------------------------------
template<int BM, int BN, int MODE>
__global__ __launch_bounds__(256) void gemm_bk64(
    const short* __restrict__ A, const short* __restrict__ W,
    const float* __restrict__ bias, const float* __restrict__ resid,
    void* __restrict__ out0, void* __restrict__ out1, void* __restrict__ out2,
    const float* __restrict__ b1, const float* __restrict__ b2,
    int N, int K, int LDK, float scale)
{
  constexpr int FM = BM / 32, FN = BN / 32;
  __shared__ __align__(16) short Alds[BM * 64];
  __shared__ __align__(16) short Blds[BN * 64];
  const int tid = threadIdx.x, lane = tid & 63, wave = tid >> 6;
  const int wr = wave >> 1, wc = wave & 1;
  const int m0 = blockIdx.x * BM, n0 = blockIdx.y * BN;
  const int bz = blockIdx.z;
  const int lr = lane & 15;               // fragment row
  const int kc = (lane >> 4) * 8;         // fragment k sub-offset
  const size_t koff = (size_t)bz * K;

  f32x4 acc[FM][FN];
#pragma unroll
  for (int mi = 0; mi < FM; ++mi)
#pragma unroll
    for (int ni = 0; ni < FN; ++ni)
      acc[mi][ni] = (f32x4){0.f, 0.f, 0.f, 0.f};

  const int nk = K >> 6;
  for (int kt = 0; kt < nk; ++kt) {
    const int k0 = kt << 6;
#pragma unroll
    for (int j = 0; j < BM / 32; ++j) {
      const int i = wave + 4 * j;          // issue index in [0, BM/8)
      const int rb = i >> 1, kk = i & 1;
      gload16(A + (size_t)(m0 + rb * 16 + lr) * LDK + koff + k0 + kk * 32 + kc,
              &Alds[i * 512]);
    }
#pragma unroll
    for (int j = 0; j < BN / 32; ++j) {
      const int i = wave + 4 * j;
      const int rb = i >> 1, kk = i & 1;
      gload16(W + (size_t)(n0 + rb * 16 + lr) * LDK + koff + k0 + kk * 32 + kc,
              &Blds[i * 512]);
    }
    __syncthreads();
    bf16x8 af[2][FM], bfv[2][FN];
#pragma unroll
    for (int kk = 0; kk < 2; ++kk) {
#pragma unroll
      for (int mi = 0; mi < FM; ++mi)
        af[kk][mi] = *reinterpret_cast<const bf16x8*>(
            &Alds[((wr * FM + mi) * 2 + kk) * 512 + lane * 8]);
#pragma unroll
      for (int ni = 0; ni < FN; ++ni)
        bfv[kk][ni] = *reinterpret_cast<const bf16x8*>(
            &Blds[((wc * FN + ni) * 2 + kk) * 512 + lane * 8]);
    }
#pragma unroll
    for (int kk = 0; kk < 2; ++kk)
#pragma unroll
      for (int mi = 0; mi < FM; ++mi)
#pragma unroll
        for (int ni = 0; ni < FN; ++ni)
          acc[mi][ni] = __builtin_amdgcn_mfma_f32_16x16x32_bf16(
              af[kk][mi], bfv[kk][ni], acc[mi][ni], 0, 0, 0);
    __syncthreads();
  }

  // epilogue: C/D col = lane&15, row = (lane>>4)*4 + reg
  const int cn = lane & 15;
  const int rb = (lane >> 4) * 4;
#pragma unroll
  for (int mi = 0; mi < FM; ++mi)
#pragma unroll
    for (int ni = 0; ni < FN; ++ni)
#pragma unroll
      for (int j = 0; j < 4; ++j) {
        const int row = m0 + wr * (BM / 2) + mi * 16 + rb + j;
        const int col = n0 + wc * (BN / 2) + ni * 16 + cn;
        const float a = acc[mi][ni][j];
        if (MODE == 0) {
          ((float*)out0)[(size_t)row * N + col] =
              a + bias[col] + resid[(size_t)row * N + col];
        } else if (MODE == 1) {
          ((short*)out0)[(size_t)row * N + col] = f2bf((a + bias[col]) * scale);
        } else if (MODE == 2) {
          float t = a + bias[col];
          t = 0.5f * t * (1.f + erff(t * 0.70710678118654752f));
          ((short*)out0)[(size_t)row * N + col] = f2bf(t);
        } else if (MODE == 3) {
          const int rg  = n0 / 1280;
          const int cl  = col - rg * 1280;
          short* op     = rg == 0 ? (short*)out0 : rg == 1 ? (short*)out1 : (short*)out2;
          const float* bp = rg == 0 ? bias : rg == 1 ? b1 : b2;
          const float sc  = rg == 0 ? 0.125f : 1.f;
          op[(size_t)row * 1280 + cl] = f2bf((a + bp[cl]) * sc);
        } else {
          float* op = bz == 0 ? (float*)out0 : (float*)out1;
          op[(size_t)row * N + col] = a;
        }
      }
}

// ---------------------------------------------------------------------------
// down-proj reduction: out = p0 + p1 + bias + resid   (fp32, float4)
// ---------------------------------------------------------------------------
__global__ __launch_bounds__(256) void reduce_down(
    const float* __restrict__ p0, const float* __restrict__ p1,
    const float* __restrict__ resid, const float* __restrict__ bias,
    float* __restrict__ out)
{
  const size_t i = ((size_t)blockIdx.x * 256 + threadIdx.x) * 4;
  if (i >= (size_t)S1) return;
  const int col = (int)(i % HIDn);
  const float4 a = *reinterpret_cast<const float4*>(p0 + i);
  const float4 b = *reinterpret_cast<const float4*>(p1 + i);
  const float4 r = *reinterpret_cast<const float4*>(resid + i);
  const float4 bi = *reinterpret_cast<const float4*>(bias + col);
  float4 o;
  o.x = a.x + b.x + r.x + bi.x;
  o.y = a.y + b.y + r.y + bi.y;
  o.z = a.z + b.z + r.z + bi.z;
  o.w = a.w + b.w + r.w + bi.w;
  *reinterpret_cast<float4*>(out + i) = o;
}

// ---------------------------------------------------------------------------
// MFMA flash attention, all-bf16 K/V caches (row-major, PADK keys/panel).
// 1-D grid of 640 blocks, XCD-chunk swizzled (4 q-tiles per (b,h) share XCD).
// Block = 4 waves; each wave owns 16 q-rows of a 64-row Q tile; 64-key chunks.
// ---------------------------------------------------------------------------
template<bool HASMASK>
__global__ __launch_bounds__(256) void attn_mfma(
    const short* __restrict__ Qb, const short* __restrict__ Kc,
    const short* __restrict__ Vc, const float* __restrict__ mask,
    short* __restrict__ Ob, int PADK, int KT)
{
  const int orig = blockIdx.x;                  // 640 = 4*Hn*Bc
  const int idx  = (orig & 7) * 80 + (orig >> 3);
  const int qt = idx & 3;
  const int h  = (idx >> 2) % Hn;
  const int b  = idx / (4 * Hn);
  const int bh = b * Hn + h;
  const int tid = threadIdx.x, lane = tid & 63, wave = tid >> 6;
  const int q0 = qt * 64;
  const int cn = lane & 15;
  const int hg = lane >> 4;
  const int rb = hg * 4;

  __shared__ __align__(16) short k_s[64][72];
  __shared__ __align__(16) short vt_s[64][72];
  __shared__ __align__(16) short p_s[4][16][72];

  bf16x8 aq[2];
  {
    const short* qrow = Qb + (size_t)(b * Qn + q0 + wave * 16 + cn) * HIDn + h * 64;
    aq[0] = *reinterpret_cast<const bf16x8*>(qrow + hg * 8);
    aq[1] = *reinterpret_cast<const bf16x8*>(qrow + 32 + hg * 8);
  }

  float mrun[4] = {-1e30f, -1e30f, -1e30f, -1e30f};
  float lrun[4] = {0.f, 0.f, 0.f, 0.f};
  f32x4 oacc[4];
#pragma unroll
  for (int t = 0; t < 4; ++t) oacc[t] = (f32x4){0.f, 0.f, 0.f, 0.f};

  const int nchunk = PADK >> 6;
  for (int ci = 0; ci < nchunk; ++ci) {
    const int c0 = ci * 64;
    const short* kbase = Kc + ((size_t)bh * PADK + c0) * 64;
    const short* vbase = Vc + ((size_t)bh * PADK + c0) * 64;
#pragma unroll
    for (int r = 0; r < 2; ++r) {
      const int i = tid + r * 256;
      const int key = i >> 3, d8 = (i & 7) * 8;
      const bf16x8 kv = *reinterpret_cast<const bf16x8*>(kbase + key * 64 + d8);
      const bf16x8 vv = *reinterpret_cast<const bf16x8*>(vbase + key * 64 + d8);
      *reinterpret_cast<bf16x8*>(&k_s[key][d8]) = kv;
      const int g = key >> 3, o = key & 7, f = i & 7;   // f = (d8>>3)&7
      const int col = ((g ^ f) << 3) | o;
#pragma unroll
      for (int j = 0; j < 8; ++j) vt_s[d8 + j][col] = vv[j];
    }
    __syncthreads();

    // QK^T
    f32x4 sacc[4];
#pragma unroll
    for (int t = 0; t < 4; ++t) sacc[t] = (f32x4){0.f, 0.f, 0.f, 0.f};
#pragma unroll
    for (int t = 0; t < 4; ++t)
#pragma unroll
      for (int kk = 0; kk < 2; ++kk) {
        const bf16x8 bk = *reinterpret_cast<const bf16x8*>(&k_s[t * 16 + cn][kk * 32 + hg * 8]);
        sacc[t] = __builtin_amdgcn_mfma_f32_16x16x32_bf16(aq[kk], bk, sacc[t], 0, 0, 0);
      }

    float sc[4][4];
#pragma unroll
    for (int t = 0; t < 4; ++t) {
      const int key = c0 + t * 16 + cn;
      const bool valid = key < KT;
#pragma unroll
      for (int j = 0; j < 4; ++j) {
        float v = sacc[t][j];
        if (HASMASK && valid)
          v += mask[((size_t)(b * Qn) + q0 + wave * 16 + rb + j) * KT + key];
        sc[t][j] = valid ? v : -1e30f;
      }
    }

    // online softmax with deferred rescale (THR = 8)
#pragma unroll
    for (int j = 0; j < 4; ++j) {
      float mx = fmaxf(fmaxf(sc[0][j], sc[1][j]), fmaxf(sc[2][j], sc[3][j]));
#pragma unroll
      for (int off = 1; off < 16; off <<= 1) mx = fmaxf(mx, __shfl_xor(mx, off, 64));
      if (mx > mrun[j] + 8.f) {
        const float alpha = __expf(mrun[j] - mx);
        lrun[j] *= alpha;
#pragma unroll
        for (int t = 0; t < 4; ++t) oacc[t][j] *= alpha;
        mrun[j] = mx;
      }
      float ps = 0.f;
#pragma unroll
      for (int t = 0; t < 4; ++t) {
        const float p = __expf(sc[t][j] - mrun[j]);
        sc[t][j] = p; ps += p;
      }
#pragma unroll
      for (int off = 1; off < 16; off <<= 1) ps += __shfl_xor(ps, off, 64);
      lrun[j] += ps;
    }

    // P -> per-wave LDS slice (same-wave RAW)
#pragma unroll
    for (int t = 0; t < 4; ++t)
#pragma unroll
      for (int j = 0; j < 4; ++j)
        p_s[wave][rb + j][t * 16 + cn] = f2bf(sc[t][j]);

    // PV
    const bf16x8 ap0 = *reinterpret_cast<const bf16x8*>(&p_s[wave][cn][hg * 8]);
    const bf16x8 ap1 = *reinterpret_cast<const bf16x8*>(&p_s[wave][cn][32 + hg * 8]);
#pragma unroll
    for (int t = 0; t < 4; ++t) {
      const int d  = t * 16 + cn;
      const int fd = (d >> 3) & 7;
      const bf16x8 bv0 = *reinterpret_cast<const bf16x8*>(&vt_s[d][((hg)     ^ fd) << 3]);
      const bf16x8 bv1 = *reinterpret_cast<const bf16x8*>(&vt_s[d][((4 + hg) ^ fd) << 3]);
      oacc[t] = __builtin_amdgcn_mfma_f32_16x16x32_bf16(ap0, bv0, oacc[t], 0, 0, 0);
      oacc[t] = __builtin_amdgcn_mfma_f32_16x16x32_bf16(ap1, bv1, oacc[t], 0, 0, 0);
    }
    __syncthreads();
  }

#pragma unroll
  for (int t = 0; t < 4; ++t)
#pragma unroll
    for (int j = 0; j < 4; ++j)
      Ob[(size_t)(b * Qn + q0 + wave * 16 + rb + j) * HIDn + h * 64 + t * 16 + cn] =
          f2bf(oacc[t][j] / lrun[j]);
}

// ---------------------------------------------------------------------------
// present_key/value: bf16 new K/V rows (Q-C)..Q-1 -> fp32 (B,H,C,D)
// ---------------------------------------------------------------------------
__global__ __launch_bounds__(256) void copy_present(
    const short* __restrict__ kn, const short* __restrict__ vn,
    float* __restrict__ outk, float* __restrict__ outv)
{
  const int idx = blockIdx.x * 256 + threadIdx.x;      // over B*H*C*8 chunks
  if (idx >= Bc * Hn * Cn * 8) return;
  const int d8 = (idx & 7) * 8;
  int t = idx >> 3;
  const int c = t % Cn; t /= Cn;
  const int h = t % Hn;
  const int b = t / Hn;
  const size_t src = (size_t)(b * Qn + (Qn - Cn) + c) * HIDn + h * 64 + d8;
  const size_t dst = (((size_t)b * Hn + h) * Cn + c) * 64 + d8;
  const bf16x8 kv = *reinterpret_cast<const bf16x8*>(kn + src);
  const bf16x8 vv = *reinterpret_cast<const bf16x8*>(vn + src);
#pragma unroll
  for (int j = 0; j < 8; ++j) {
    outk[dst + j] = bf2f(kv[j]);
    outv[dst + j] = bf2f(vv[j]);
  }
}

// ---------------------------------------------------------------------------
extern "C" void kernel_launch(void* const* d_in, const int* in_sizes, int n_in,
                              void* d_out, int out_size, void* d_ws, size_t ws_size,
                              hipStream_t stream)
{
  const float* hidden  = (const float*)d_in[0];
  const float* mask    = (const float*)d_in[1];
  const float* past_k  = (const float*)d_in[2];
  const float* past_v  = (const float*)d_in[3];
  const float* cross_k = (const float*)d_in[4];
  const float* cross_v = (const float*)d_in[5];
  const float* q_w  = (const float*)d_in[6];  const float* q_b  = (const float*)d_in[7];
  const float* k_w  = (const float*)d_in[8];  const float* k_b  = (const float*)d_in[9];
  const float* v_w  = (const float*)d_in[10]; const float* v_b  = (const float*)d_in[11];
  const float* o_w  = (const float*)d_in[12]; const float* o_b  = (const float*)d_in[13];
  const float* cq_w = (const float*)d_in[14]; const float* cq_b = (const float*)d_in[15];
  const float* co_w = (const float*)d_in[16]; const float* co_b = (const float*)d_in[17];
  const float* up_w = (const float*)d_in[18]; const float* up_b = (const float*)d_in[19];
  const float* dn_w = (const float*)d_in[20]; const float* dn_b = (const float*)d_in[21];
  const float* ln1w = (const float*)d_in[22]; const float* ln1b = (const float*)d_in[23];
  const float* ln2w = (const float*)d_in[24]; const float* ln2b = (const float*)d_in[25];
  const float* ln3w = (const float*)d_in[26]; const float* ln3b = (const float*)d_in[27];

  // ---- workspace layout ----
  short* wq  = (short*)d_ws;
  short* wk  = wq  + (size_t)WSZ;
  short* wv  = wk  + (size_t)WSZ;
  short* wo  = wv  + (size_t)WSZ;
  short* wcq = wo  + (size_t)WSZ;
  short* wco = wcq + (size_t)WSZ;
  short* wup = wco + (size_t)WSZ;
  short* wdn = wup + (size_t)HIDn * In;
  short* xb  = wdn + (size_t)HIDn * In;         // LN outputs (x1,x2,x3)
  short* qb  = xb  + (size_t)S1;                // q, reused as cq
  short* kb  = qb  + (size_t)S1;
  short* vb  = kb  + (size_t)S1;
  short* ab  = vb  + (size_t)S1;                // attn outputs
  short* U   = ab  + (size_t)S1;                // self caches, then gelu(up)
  short* ksb = U;                               // self K cache (dead by LN3)
  short* vsb = U + (size_t)BH * KSELF * 64;
  short* upa = U;                               // written after LN3
  short* kcc = U + (size_t)BQ * In;             // cross K cache
  short* vcc = kcc + (size_t)BH * EPAD * 64;
  float* h1  = (float*)(vcc + (size_t)BH * EPAD * 64);
  // down-proj split-K partials alias dead qb..ab
  float* p0  = (float*)qb;                      // spans qb+kb
  float* p1  = (float*)vb;                      // spans vb+ab

  float* out_h  = (float*)d_out;
  float* out_pk = out_h + (size_t)S1;
  float* out_pv = out_pk + (size_t)(Bc * Hn * Cn * Dn);
  float* h2 = out_h;                            // h2 aliases final output

  const dim3 blk(256);
  const dim3 gconv(3200, 8);
  const dim3 gqkv(16, 30);         // 2048/128 x 3840/128
  const dim3 gn64(16, 20);         // 2048/128 x 1280/64
  const dim3 gup(16, 40);          // 2048/128 x 5120/128
  const dim3 gdn(16, 20, 2);       // down split-K=2
  const dim3 gattn(640);           // 4 * Hn * Bc, XCD-swizzled in-kernel

  // weights -> bf16
  convert_all<<<gconv, blk, 0, stream>>>(q_w, k_w, v_w, o_w, cq_w, co_w, up_w, dn_w,
                                         wq, wk, wv, wo, wcq, wco, wup, wdn);
  // cross K/V -> bf16 caches (padded to 1536 keys)
  prep_cross<<<(BH * EPAD * 8) / 256, blk, 0, stream>>>(cross_k, cross_v, kcc, vcc);
  // x1 = LN1(hidden)
  layernorm_k<<<BQ, blk, 0, stream>>>(hidden, ln1w, ln1b, xb);
  // q,k,v fused GEMM (q scaled 0.125 in epilogue)
  gemm_bk64<128, 128, 3><<<gqkv, blk, 0, stream>>>(xb, wq, q_b, nullptr,
      qb, kb, vb, k_b, v_b, 3840, HIDn, HIDn, 1.f);
  // present kv
  copy_present<<<(Bc * Hn * Cn * 8 + 255) / 256, blk, 0, stream>>>(kb, vb, out_pk, out_pv);
  // self K/V caches (past fp32 + new bf16)
  prep_self<<<(BH * KSELF * 8) / 256, blk, 0, stream>>>(past_k, past_v, kb, vb, ksb, vsb);
  // self attention -> ab
  attn_mfma<true><<<gattn, blk, 0, stream>>>(qb, ksb, vsb, mask, ab, KSELF, KSELF);
  // h1 = hidden + ab Wo^T + bo
  gemm_bk64<128, 64, 0><<<gn64, blk, 0, stream>>>(ab, wo, o_b, hidden,
      h1, nullptr, nullptr, nullptr, nullptr, HIDn, HIDn, HIDn, 1.f);
  // x2 = LN2(h1)
  layernorm_k<<<BQ, blk, 0, stream>>>(h1, ln2w, ln2b, xb);
  // cq = (x2 Wcq^T + b)*0.125  (reuse qb)
  gemm_bk64<128, 64, 1><<<gn64, blk, 0, stream>>>(xb, wcq, cq_b, nullptr,
      qb, nullptr, nullptr, nullptr, nullptr, HIDn, HIDn, HIDn, 0.125f);
  // cross attention -> ab
  attn_mfma<false><<<gattn, blk, 0, stream>>>(qb, kcc, vcc, nullptr, ab, EPAD, En);
  // h2 = h1 + ab Wco^T + b   (h2 aliases out_h)
  gemm_bk64<128, 64, 0><<<gn64, blk, 0, stream>>>(ab, wco, co_b, h1,
      h2, nullptr, nullptr, nullptr, nullptr, HIDn, HIDn, HIDn, 1.f);
  // x3 = LN3(h2)
  layernorm_k<<<BQ, blk, 0, stream>>>(h2, ln3w, ln3b, xb);
  // upa = gelu(x3 Wup^T + b)
  gemm_bk64<128, 128, 2><<<gup, blk, 0, stream>>>(xb, wup, up_b, nullptr,
      upa, nullptr, nullptr, nullptr, nullptr, In, HIDn, HIDn, 1.f);
  // down-proj split-K=2 partials
  gemm_bk64<128, 64, 4><<<gdn, blk, 0, stream>>>(upa, wdn, nullptr, nullptr,
      p0, p1, nullptr, nullptr, nullptr, HIDn, In / 2, In, 1.f);
  // out_h = p0 + p1 + dn_b + h2  (in-place over h2)
  reduce_down<<<(S1 / 4 + 255) / 256, blk, 0, stream>>>(p0, p1, h2, dn_b, out_h);
}